// Round 1
// baseline (1292.577 us; speedup 1.0000x reference)
//
#include <hip/hip_runtime.h>
#include <math.h>

#define B_ 2
#define C_ 256
#define Dp_ 16
#define H_ 16
#define W_ 16
#define L_ 4096
#define BL_ 8192
#define DEPTH_ 4

__device__ __forceinline__ float silu_(float x){ return x/(1.f+__expf(-x)); }
__device__ __forceinline__ float softplus_(float x){ return fmaxf(x,0.f)+log1pf(__expf(-fabsf(x))); }

// ---------------- transpose in: x (B,C,D,H,W) -> t [B][L][C], l=(h*16+w)*16+d ----------------
__global__ __launch_bounds__(256) void k_t_in(const float* __restrict__ x, float* __restrict__ t)
{
    __shared__ float tile[16*257];
    int blk=blockIdx.x, b=blk>>8, d=(blk>>4)&15, h=blk&15;
    int tid=threadIdx.x;
    int w2=tid&15;
    for(int p=0;p<16;p++){
        int c=(tid>>4)+16*p;
        tile[w2*257+c]=x[((size_t)(b*C_+c))*4096 + d*256 + h*16 + w2];
    }
    __syncthreads();
    for(int k=0;k<16;k++){
        t[((size_t)b*L_+(h*16+k)*16+d)*C_+tid]=tile[k*257+tid];
    }
}

// ---------------- LN1 + in_proj: t -> xs (first 256 cols), z (last 256 cols) ----------------
__global__ __launch_bounds__(256) void k_ln_inproj(
    const float* __restrict__ t, const float* __restrict__ inw,
    const float* __restrict__ g, const float* __restrict__ be,
    float* __restrict__ xs, float* __restrict__ z)
{
    __shared__ float hb[16*256];
    __shared__ float mrs[16][2];
    int tid=threadIdx.x;
    size_t row0=(size_t)blockIdx.x*16;
    const float* src=t+row0*C_;
    for(int k=0;k<16;k++) hb[k*256+tid]=src[k*256+tid];
    __syncthreads();
    int r=tid>>4, p=tid&15;
    float s=0.f, ss=0.f;
    #pragma unroll
    for(int k=0;k<16;k++){ float v=hb[r*256+k*16+p]; s+=v; ss+=v*v; }
    #pragma unroll
    for(int m=1;m<16;m<<=1){ s+=__shfl_xor(s,m); ss+=__shfl_xor(ss,m); }
    if(p==0){ float mn=s*(1.f/256.f); mrs[r][0]=mn; mrs[r][1]=rsqrtf(ss*(1.f/256.f)-mn*mn+1e-5f); }
    __syncthreads();
    {
        float gg=g[tid], bb=be[tid];
        #pragma unroll
        for(int k=0;k<16;k++){
            float v=hb[k*256+tid];
            hb[k*256+tid]=(v-mrs[k][0])*mrs[k][1]*gg+bb;
        }
    }
    __syncthreads();
    float acc0[16], acc1[16];
    #pragma unroll
    for(int i=0;i<16;i++){acc0[i]=0.f;acc1[i]=0.f;}
    const float4* w0=(const float4*)(inw+(size_t)tid*C_);
    const float4* w1=(const float4*)(inw+(size_t)(tid+256)*C_);
    for(int k4=0;k4<64;k4++){
        float4 a=w0[k4], b4=w1[k4];
        #pragma unroll
        for(int i=0;i<16;i++){
            const float4 hv=*(const float4*)&hb[i*256+k4*4];
            acc0[i]=fmaf(hv.x,a.x,fmaf(hv.y,a.y,fmaf(hv.z,a.z,fmaf(hv.w,a.w,acc0[i]))));
            acc1[i]=fmaf(hv.x,b4.x,fmaf(hv.y,b4.y,fmaf(hv.z,b4.z,fmaf(hv.w,b4.w,acc1[i]))));
        }
    }
    float* xsp=xs+row0*C_+tid;
    float* zp =z +row0*C_+tid;
    #pragma unroll
    for(int i=0;i<16;i++){ xsp[(size_t)i*C_]=acc0[i]; zp[(size_t)i*C_]=acc1[i]; }
}

// ---------------- depthwise conv3x3x3 + bias + SiLU + flip-write -> seq ----------------
__global__ __launch_bounds__(256) void k_conv(
    const float* __restrict__ xs, const float* __restrict__ cw,
    const float* __restrict__ cb, float* __restrict__ seq, int ori)
{
    __shared__ float wl[256*27];
    int tid=threadIdx.x;
    for(int j=tid;j<256*27;j+=256) wl[j]=cw[j];
    int bl=blockIdx.x;
    int b=bl>>12, l=bl&4095;
    int d=l&15, w=(l>>4)&15, h=l>>8;
    __syncthreads();
    const float* base=xs+((size_t)b*L_)*C_+tid;
    const float* wp=wl+tid*27;
    float acc=cb[tid];
    #pragma unroll
    for(int kh=0;kh<3;kh++){
        int hh=h+kh-1; if((unsigned)hh>=16u) continue;
        #pragma unroll
        for(int kw=0;kw<3;kw++){
            int ww=w+kw-1; if((unsigned)ww>=16u) continue;
            #pragma unroll
            for(int kd=0;kd<3;kd++){
                int dd=d+kd-1; if((unsigned)dd>=16u) continue;
                acc=fmaf(wp[(kh*3+kw)*3+kd], base[(size_t)((hh*16+ww)*16+dd)*C_], acc);
            }
        }
    }
    acc=silu_(acc);
    int hf=(ori&1)?15-h:h;
    int wf=(ori&2)?15-w:w;
    int df=(ori&4)?15-d:d;
    seq[((size_t)b*L_+(hf*16+wf)*16+df)*C_+tid]=acc;
}

// ---------------- xproj (48 cols) + dt proj (256 cols, softplus) ----------------
__global__ __launch_bounds__(256) void k_xproj(
    const float* __restrict__ seq, const float* __restrict__ xw,
    const float* __restrict__ dtw, const float* __restrict__ dtbias,
    float* __restrict__ dt, float* __restrict__ BC)
{
    __shared__ float hb[16*256];
    __shared__ float dbl[16][48];
    int tid=threadIdx.x;
    size_t row0=(size_t)blockIdx.x*16;
    const float* src=seq+row0*C_;
    for(int k=0;k<16;k++) hb[k*256+tid]=src[k*256+tid];
    __syncthreads();
    {
        int r=tid>>4, j=tid&15;
        const float4* wa=(const float4*)(xw+(size_t)j*C_);
        const float4* wb=(const float4*)(xw+(size_t)(j+16)*C_);
        const float4* wc=(const float4*)(xw+(size_t)(j+32)*C_);
        float a=0.f,b=0.f,c=0.f;
        for(int k4=0;k4<64;k4++){
            const float4 hv=*(const float4*)&hb[r*256+k4*4];
            float4 xa=wa[k4],xb=wb[k4],xc=wc[k4];
            a=fmaf(hv.x,xa.x,fmaf(hv.y,xa.y,fmaf(hv.z,xa.z,fmaf(hv.w,xa.w,a))));
            b=fmaf(hv.x,xb.x,fmaf(hv.y,xb.y,fmaf(hv.z,xb.z,fmaf(hv.w,xb.w,b))));
            c=fmaf(hv.x,xc.x,fmaf(hv.y,xc.y,fmaf(hv.z,xc.z,fmaf(hv.w,xc.w,c))));
        }
        dbl[r][j]=a; dbl[r][j+16]=b; dbl[r][j+32]=c;
    }
    __syncthreads();
    {
        int e=tid, r2=e>>5, j2=e&31;
        BC[(row0+r2)*32+j2]=dbl[r2][16+j2];
        e=tid+256; r2=e>>5; j2=e&31;
        BC[(row0+r2)*32+j2]=dbl[r2][16+j2];
    }
    float wreg[16];
    #pragma unroll
    for(int j=0;j<16;j++) wreg[j]=dtw[tid*16+j];
    float bb=dtbias[tid];
    for(int r2=0;r2<16;r2++){
        float acc=bb;
        #pragma unroll
        for(int j=0;j<16;j++) acc=fmaf(dbl[r2][j],wreg[j],acc);
        dt[(row0+r2)*C_+tid]=softplus_(acc);
    }
}

// ---------------- chunked selective scan ----------------
// pass 1: per chunk (256 steps): Aprod = prod(dA), Hout = local end-state (h_init=0)
__global__ __launch_bounds__(64) void k_scan1(
    const float* __restrict__ dt, const float* __restrict__ seq,
    const float* __restrict__ BC, const float* __restrict__ A_log,
    float* __restrict__ Ap, float* __restrict__ Ho)
{
    int lane=threadIdx.x, grp=lane>>4, n=lane&15;
    int blk=blockIdx.x, pg=blk>>4, ck=blk&15;
    int pair=pg*4+grp, b=pair>>8, c=pair&255;
    float An=-__expf(A_log[c*16+n]);
    size_t base=(size_t)b*L_*C_+c;
    const float* bcp=BC+(size_t)b*L_*32;
    float carry=0.f, ap=1.f;
    int l0=ck*256;
    #pragma unroll 4
    for(int l=l0;l<l0+256;l++){
        float dtv=dt[base+(size_t)l*C_];
        float xv =seq[base+(size_t)l*C_];
        float bv =bcp[l*32+n];
        float dA=__expf(dtv*An);
        carry=fmaf(dA,carry,dtv*bv*xv);
        ap*=dA;
    }
    int idx=(pair*16+ck)*16+n;
    Ap[idx]=ap; Ho[idx]=carry;
}

// pass 2: serial chain over the 16 chunk summaries; Sb[ck] = state entering chunk ck
__global__ __launch_bounds__(64) void k_scan2(
    const float* __restrict__ Ap, const float* __restrict__ Ho, float* __restrict__ Sb)
{
    int gid=blockIdx.x*64+threadIdx.x;   // 0..8191 over (pair, n)
    int pair=gid>>4, n=gid&15;
    float S=0.f;
    #pragma unroll
    for(int ck=0;ck<16;ck++){
        int idx=(pair*16+ck)*16+n;
        Sb[idx]=S;
        S=fmaf(Ap[idx],S,Ho[idx]);
    }
}

// pass 3: replay chunk from correct init; emit y = C.h + D*x
__global__ __launch_bounds__(64) void k_scan3(
    const float* __restrict__ dt, const float* __restrict__ seq,
    const float* __restrict__ BC, const float* __restrict__ A_log,
    const float* __restrict__ Dsk, const float* __restrict__ Sb,
    float* __restrict__ y)
{
    int lane=threadIdx.x, grp=lane>>4, n=lane&15;
    int blk=blockIdx.x, pg=blk>>4, ck=blk&15;
    int pair=pg*4+grp, b=pair>>8, c=pair&255;
    float An=-__expf(A_log[c*16+n]);
    float Dc=Dsk[c];
    size_t base=(size_t)b*L_*C_+c;
    const float* bcp=BC+(size_t)b*L_*32;
    float carry=Sb[(pair*16+ck)*16+n];
    int l0=ck*256;
    #pragma unroll 4
    for(int l=l0;l<l0+256;l++){
        float dtv=dt[base+(size_t)l*C_];
        float xv =seq[base+(size_t)l*C_];
        float bv =bcp[l*32+n];
        float cv =bcp[l*32+16+n];
        float dA=__expf(dtv*An);
        carry=fmaf(dA,carry,dtv*bv*xv);
        float part=carry*cv;
        part+=__shfl_xor(part,1);
        part+=__shfl_xor(part,2);
        part+=__shfl_xor(part,4);
        part+=__shfl_xor(part,8);
        if(n==0) y[base+(size_t)l*C_]=fmaf(Dc,xv,part);
    }
}

// ---------------- unflip + out-LN + gate by SiLU(z) -> y2 ----------------
__global__ __launch_bounds__(256) void k_post(
    const float* __restrict__ y, const float* __restrict__ z,
    const float* __restrict__ og, const float* __restrict__ ob,
    float* __restrict__ y2, int ori)
{
    __shared__ float red[8];
    int c=threadIdx.x;
    int bl=blockIdx.x, b=bl>>12, l=bl&4095;
    int d=l&15, w=(l>>4)&15, h=l>>8;
    int hf=(ori&1)?15-h:h, wf=(ori&2)?15-w:w, df=(ori&4)?15-d:d;
    int lf=(hf*16+wf)*16+df;
    float v=y[((size_t)b*L_+lf)*C_+c];
    float s=v, ss=v*v;
    #pragma unroll
    for(int m=32;m>=1;m>>=1){ s+=__shfl_xor(s,m); ss+=__shfl_xor(ss,m); }
    if((c&63)==0){ red[(c>>6)*2]=s; red[(c>>6)*2+1]=ss; }
    __syncthreads();
    s=red[0]+red[2]+red[4]+red[6];
    ss=red[1]+red[3]+red[5]+red[7];
    float mn=s*(1.f/256.f);
    float rstd=rsqrtf(ss*(1.f/256.f)-mn*mn+1e-5f);
    float yn=(v-mn)*rstd*og[c]+ob[c];
    float zv=z[((size_t)b*L_+l)*C_+c];
    y2[((size_t)b*L_+l)*C_+c]=yn*silu_(zv);
}

// ---------------- out GEMM (256x256) + residual into t ----------------
__global__ __launch_bounds__(256) void k_out(
    const float* __restrict__ y2, const float* __restrict__ ow,
    float* __restrict__ t)
{
    __shared__ float hb[16*256];
    int tid=threadIdx.x;
    size_t row0=(size_t)blockIdx.x*16;
    const float* src=y2+row0*C_;
    for(int k=0;k<16;k++) hb[k*256+tid]=src[k*256+tid];
    __syncthreads();
    float acc[16];
    #pragma unroll
    for(int i=0;i<16;i++)acc[i]=0.f;
    const float4* wr=(const float4*)(ow+(size_t)tid*C_);
    for(int k4=0;k4<64;k4++){
        float4 a=wr[k4];
        #pragma unroll
        for(int i=0;i<16;i++){
            const float4 hv=*(const float4*)&hb[i*256+k4*4];
            acc[i]=fmaf(hv.x,a.x,fmaf(hv.y,a.y,fmaf(hv.z,a.z,fmaf(hv.w,a.w,acc[i]))));
        }
    }
    float* tp=t+row0*C_+tid;
    #pragma unroll
    for(int i=0;i<16;i++) tp[(size_t)i*C_]+=acc[i];
}

// ---------------- final LN + transpose out: t -> out (B,C,D,H,W) ----------------
__global__ __launch_bounds__(256) void k_final(
    const float* __restrict__ t, const float* __restrict__ pg,
    const float* __restrict__ pb, float* __restrict__ out)
{
    __shared__ float tile[16*257];
    __shared__ float mrs[16][2];
    int blk=blockIdx.x, b=blk>>8, d=(blk>>4)&15, h=blk&15;
    int tid=threadIdx.x;
    for(int w2=0;w2<16;w2++){
        tile[w2*257+tid]=t[((size_t)b*L_+(h*16+w2)*16+d)*C_+tid];
    }
    __syncthreads();
    int r=tid>>4, p=tid&15;
    float s=0.f, ss=0.f;
    #pragma unroll
    for(int k=0;k<16;k++){ float v=tile[r*257+k*16+p]; s+=v; ss+=v*v; }
    #pragma unroll
    for(int m=1;m<16;m<<=1){ s+=__shfl_xor(s,m); ss+=__shfl_xor(ss,m); }
    if(p==0){ float mn=s*(1.f/256.f); mrs[r][0]=mn; mrs[r][1]=rsqrtf(ss*(1.f/256.f)-mn*mn+1e-5f); }
    __syncthreads();
    int w2=tid&15;
    for(int p2=0;p2<16;p2++){
        int c=(tid>>4)+16*p2;
        float v=tile[w2*257+c];
        float vn=(v-mrs[w2][0])*mrs[w2][1]*pg[c]+pb[c];
        out[((size_t)(b*C_+c))*4096 + d*256 + h*16 + w2]=vn;
    }
}

extern "C" void kernel_launch(void* const* d_in, const int* in_sizes, int n_in,
                              void* d_out, int out_size, void* d_ws, size_t ws_size,
                              hipStream_t stream)
{
    (void)in_sizes; (void)n_in; (void)out_size; (void)ws_size;
    const float* x      =(const float*)d_in[0];
    const float* in_w   =(const float*)d_in[1];
    const float* conv_w =(const float*)d_in[2];
    const float* conv_b =(const float*)d_in[3];
    const float* xproj_w=(const float*)d_in[4];
    const float* dt_w   =(const float*)d_in[5];
    const float* dt_b   =(const float*)d_in[6];
    const float* A_log  =(const float*)d_in[7];
    const float* D_skip =(const float*)d_in[8];
    const float* on_g   =(const float*)d_in[9];
    const float* on_b   =(const float*)d_in[10];
    const float* out_w  =(const float*)d_in[11];
    const float* ln1_g  =(const float*)d_in[12];
    const float* ln1_b  =(const float*)d_in[13];
    const float* post_g =(const float*)d_in[14];
    const float* post_b =(const float*)d_in[15];
    float* out=(float*)d_out;
    float* ws=(float*)d_ws;

    const size_t NBL=(size_t)BL_*C_;     // 2,097,152 floats
    float* t   = ws;                      // residual stream [B][L][C]
    float* xs  = ws +   NBL;              // xs, later reused as y
    float* z   = ws + 2*NBL;
    float* seq = ws + 3*NBL;              // seq, later reused as y2
    float* dtb = ws + 4*NBL;
    float* BC  = ws + 5*NBL;              // [B*L][32] (Bm | Cm)
    float* Ap  = BC + (size_t)BL_*32;     // 512*16*16 chunk summaries
    float* Ho  = Ap + 512*16*16;
    float* Sb  = Ho + 512*16*16;

    k_t_in<<<512,256,0,stream>>>(x,t);
    for(int i=0;i<DEPTH_;i++){
        int ori=i&7;
        k_ln_inproj<<<512,256,0,stream>>>(t, in_w+(size_t)i*512*256, ln1_g+i*256, ln1_b+i*256, xs, z);
        k_conv<<<8192,256,0,stream>>>(xs, conv_w+(size_t)i*6912, conv_b+i*256, seq, ori);
        k_xproj<<<512,256,0,stream>>>(seq, xproj_w+(size_t)i*12288, dt_w+(size_t)i*4096, dt_b+i*256, dtb, BC);
        k_scan1<<<2048,64,0,stream>>>(dtb, seq, BC, A_log+(size_t)i*4096, Ap, Ho);
        k_scan2<<<128,64,0,stream>>>(Ap, Ho, Sb);
        k_scan3<<<2048,64,0,stream>>>(dtb, seq, BC, A_log+(size_t)i*4096, D_skip+i*256, Sb, xs);
        k_post<<<8192,256,0,stream>>>(xs, z, on_g+i*256, on_b+i*256, seq, ori);
        k_out<<<512,256,0,stream>>>(seq, out_w+(size_t)i*65536, t);
    }
    k_final<<<512,256,0,stream>>>(t, post_g, post_b, out);
}

// Round 2
// 1079.399 us; speedup vs baseline: 1.1975x; 1.1975x over previous
//
#include <hip/hip_runtime.h>
#include <math.h>

#define B_ 2
#define C_ 256
#define Dp_ 16
#define H_ 16
#define W_ 16
#define L_ 4096
#define BL_ 8192
#define DEPTH_ 4
#define CK_ 64   // chunks per sequence
#define CL_ 64   // chunk length

__device__ __forceinline__ float silu_(float x){ return x/(1.f+__expf(-x)); }
__device__ __forceinline__ float softplus_(float x){ return fmaxf(x,0.f)+log1pf(__expf(-fabsf(x))); }

// ---------------- transpose in: x (B,C,D,H,W) -> t [B][L][C], l=(h*16+w)*16+d ----------------
__global__ __launch_bounds__(256) void k_t_in(const float* __restrict__ x, float* __restrict__ t)
{
    __shared__ float tile[16*257];
    int blk=blockIdx.x, b=blk>>8, d=(blk>>4)&15, h=blk&15;
    int tid=threadIdx.x;
    int w2=tid&15;
    for(int p=0;p<16;p++){
        int c=(tid>>4)+16*p;
        tile[w2*257+c]=x[((size_t)(b*C_+c))*4096 + d*256 + h*16 + w2];
    }
    __syncthreads();
    for(int k=0;k<16;k++){
        t[((size_t)b*L_+(h*16+k)*16+d)*C_+tid]=tile[k*257+tid];
    }
}

// ---------------- LN1 + in_proj: t -> xs (first 256 cols), z (last 256 cols) ----------------
__global__ __launch_bounds__(256) void k_ln_inproj(
    const float* __restrict__ t, const float* __restrict__ inw,
    const float* __restrict__ g, const float* __restrict__ be,
    float* __restrict__ xs, float* __restrict__ z)
{
    __shared__ float hb[16*256];
    __shared__ float mrs[16][2];
    int tid=threadIdx.x;
    size_t row0=(size_t)blockIdx.x*16;
    const float* src=t+row0*C_;
    for(int k=0;k<16;k++) hb[k*256+tid]=src[k*256+tid];
    __syncthreads();
    int r=tid>>4, p=tid&15;
    float s=0.f, ss=0.f;
    #pragma unroll
    for(int k=0;k<16;k++){ float v=hb[r*256+k*16+p]; s+=v; ss+=v*v; }
    #pragma unroll
    for(int m=1;m<16;m<<=1){ s+=__shfl_xor(s,m); ss+=__shfl_xor(ss,m); }
    if(p==0){ float mn=s*(1.f/256.f); mrs[r][0]=mn; mrs[r][1]=rsqrtf(ss*(1.f/256.f)-mn*mn+1e-5f); }
    __syncthreads();
    {
        float gg=g[tid], bb=be[tid];
        #pragma unroll
        for(int k=0;k<16;k++){
            float v=hb[k*256+tid];
            hb[k*256+tid]=(v-mrs[k][0])*mrs[k][1]*gg+bb;
        }
    }
    __syncthreads();
    float acc0[16], acc1[16];
    #pragma unroll
    for(int i=0;i<16;i++){acc0[i]=0.f;acc1[i]=0.f;}
    const float4* w0=(const float4*)(inw+(size_t)tid*C_);
    const float4* w1=(const float4*)(inw+(size_t)(tid+256)*C_);
    for(int k4=0;k4<64;k4++){
        float4 a=w0[k4], b4=w1[k4];
        #pragma unroll
        for(int i=0;i<16;i++){
            const float4 hv=*(const float4*)&hb[i*256+k4*4];
            acc0[i]=fmaf(hv.x,a.x,fmaf(hv.y,a.y,fmaf(hv.z,a.z,fmaf(hv.w,a.w,acc0[i]))));
            acc1[i]=fmaf(hv.x,b4.x,fmaf(hv.y,b4.y,fmaf(hv.z,b4.z,fmaf(hv.w,b4.w,acc1[i]))));
        }
    }
    float* xsp=xs+row0*C_+tid;
    float* zp =z +row0*C_+tid;
    #pragma unroll
    for(int i=0;i<16;i++){ xsp[(size_t)i*C_]=acc0[i]; zp[(size_t)i*C_]=acc1[i]; }
}

// ---------------- depthwise conv3x3x3 + bias + SiLU + flip-write -> seq ----------------
__global__ __launch_bounds__(256) void k_conv(
    const float* __restrict__ xs, const float* __restrict__ cw,
    const float* __restrict__ cb, float* __restrict__ seq, int ori)
{
    __shared__ float wl[256*27];
    int tid=threadIdx.x;
    for(int j=tid;j<256*27;j+=256) wl[j]=cw[j];
    int bl=blockIdx.x;
    int b=bl>>12, l=bl&4095;
    int d=l&15, w=(l>>4)&15, h=l>>8;
    __syncthreads();
    const float* base=xs+((size_t)b*L_)*C_+tid;
    const float* wp=wl+tid*27;
    float acc=cb[tid];
    #pragma unroll
    for(int kh=0;kh<3;kh++){
        int hh=h+kh-1; if((unsigned)hh>=16u) continue;
        #pragma unroll
        for(int kw=0;kw<3;kw++){
            int ww=w+kw-1; if((unsigned)ww>=16u) continue;
            #pragma unroll
            for(int kd=0;kd<3;kd++){
                int dd=d+kd-1; if((unsigned)dd>=16u) continue;
                acc=fmaf(wp[(kh*3+kw)*3+kd], base[(size_t)((hh*16+ww)*16+dd)*C_], acc);
            }
        }
    }
    acc=silu_(acc);
    int hf=(ori&1)?15-h:h;
    int wf=(ori&2)?15-w:w;
    int df=(ori&4)?15-d:d;
    seq[((size_t)b*L_+(hf*16+wf)*16+df)*C_+tid]=acc;
}

// ---------------- xproj (48 cols) + dt proj (softplus) + emit scan-major dtT/sxT ----------------
__global__ __launch_bounds__(256) void k_xproj(
    const float* __restrict__ seq, const float* __restrict__ xw,
    const float* __restrict__ dtw, const float* __restrict__ dtbias,
    float* __restrict__ dtT, float* __restrict__ sxT, float* __restrict__ BC)
{
    __shared__ float hb[16*256];
    __shared__ float dbl[16][48];
    int tid=threadIdx.x;
    size_t row0=(size_t)blockIdx.x*16;
    int b=(int)(row0>>12), lloc=(int)(row0&4095);
    const float* src=seq+row0*C_;
    for(int k=0;k<16;k++) hb[k*256+tid]=src[k*256+tid];
    __syncthreads();
    {
        int r=tid>>4, j=tid&15;
        const float4* wa=(const float4*)(xw+(size_t)j*C_);
        const float4* wb=(const float4*)(xw+(size_t)(j+16)*C_);
        const float4* wc=(const float4*)(xw+(size_t)(j+32)*C_);
        float a=0.f,b2=0.f,c=0.f;
        for(int k4=0;k4<64;k4++){
            const float4 hv=*(const float4*)&hb[r*256+k4*4];
            float4 xa=wa[k4],xb=wb[k4],xc=wc[k4];
            a =fmaf(hv.x,xa.x,fmaf(hv.y,xa.y,fmaf(hv.z,xa.z,fmaf(hv.w,xa.w,a ))));
            b2=fmaf(hv.x,xb.x,fmaf(hv.y,xb.y,fmaf(hv.z,xb.z,fmaf(hv.w,xb.w,b2))));
            c =fmaf(hv.x,xc.x,fmaf(hv.y,xc.y,fmaf(hv.z,xc.z,fmaf(hv.w,xc.w,c ))));
        }
        dbl[r][j]=a; dbl[r][j+16]=b2; dbl[r][j+32]=c;
    }
    __syncthreads();
    {
        int e=tid, r2=e>>5, j2=e&31;
        BC[(row0+r2)*32+j2]=dbl[r2][16+j2];
        e=tid+256; r2=e>>5; j2=e&31;
        BC[(row0+r2)*32+j2]=dbl[r2][16+j2];
    }
    // seq values transposed: sxT[b][c][l], 64B contiguous per lane
    {
        float* sp = sxT + ((size_t)(b*C_+tid))*L_ + lloc;
        #pragma unroll
        for(int q=0;q<4;q++){
            float4 v=make_float4(hb[(4*q+0)*256+tid],hb[(4*q+1)*256+tid],
                                 hb[(4*q+2)*256+tid],hb[(4*q+3)*256+tid]);
            ((float4*)sp)[q]=v;
        }
    }
    float wreg[16];
    #pragma unroll
    for(int j=0;j<16;j++) wreg[j]=dtw[tid*16+j];
    float bb=dtbias[tid];
    float dts[16];
    #pragma unroll
    for(int r2=0;r2<16;r2++){
        float acc=bb;
        #pragma unroll
        for(int j=0;j<16;j++) acc=fmaf(dbl[r2][j],wreg[j],acc);
        dts[r2]=softplus_(acc);
    }
    float* dp = dtT + ((size_t)(b*C_+tid))*L_ + lloc;
    #pragma unroll
    for(int q=0;q<4;q++){
        ((float4*)dp)[q]=make_float4(dts[4*q+0],dts[4*q+1],dts[4*q+2],dts[4*q+3]);
    }
}

// ---------------- chunked selective scan: CK_=64 chunks of CL_=64 ----------------
// block = 256 thr = 4 waves; wave handles one (pg-quad, chunk); lanes = 4 pairs x 16 n
__global__ __launch_bounds__(256) void k_scan1(
    const float* __restrict__ dtT, const float* __restrict__ sxT,
    const float* __restrict__ BC, const float* __restrict__ A_log,
    float* __restrict__ Ap, float* __restrict__ Ho)
{
    int wv=threadIdx.x>>6, lane=threadIdx.x&63;
    int grp=lane>>4, n=lane&15;
    int blk=blockIdx.x, pg=blk>>4, ck=(blk&15)*4+wv;
    int pair=pg*4+grp, b=pair>>8, c=pair&255;
    float An=-__expf(A_log[c*16+n]);
    int l0=ck*CL_;
    const float4* dp=(const float4*)(dtT+((size_t)(b*C_+c))*L_+l0);
    const float4* xp=(const float4*)(sxT+((size_t)(b*C_+c))*L_+l0);
    const float* bcp=BC+((size_t)b*L_+l0)*32+n;
    float carry=0.f, sdt=0.f;
    #pragma unroll
    for(int q=0;q<CL_/4;q++){
        float4 d4=dp[q], x4=xp[q];
        float bv;
        bv=bcp[(4*q+0)*32];{float dA=__expf(d4.x*An);carry=fmaf(dA,carry,d4.x*bv*x4.x);sdt+=d4.x;}
        bv=bcp[(4*q+1)*32];{float dA=__expf(d4.y*An);carry=fmaf(dA,carry,d4.y*bv*x4.y);sdt+=d4.y;}
        bv=bcp[(4*q+2)*32];{float dA=__expf(d4.z*An);carry=fmaf(dA,carry,d4.z*bv*x4.z);sdt+=d4.z;}
        bv=bcp[(4*q+3)*32];{float dA=__expf(d4.w*An);carry=fmaf(dA,carry,d4.w*bv*x4.w);sdt+=d4.w;}
    }
    int idx=(pair*CK_+ck)*16+n;
    Ap[idx]=__expf(An*sdt); Ho[idx]=carry;
}

// pass 2: serial chain over the chunk summaries; Sb[ck] = state entering chunk ck
__global__ __launch_bounds__(256) void k_scan2(
    const float* __restrict__ Ap, const float* __restrict__ Ho, float* __restrict__ Sb)
{
    int gid=blockIdx.x*256+threadIdx.x;   // 0..8191 over (pair, n)
    int pair=gid>>4, n=gid&15;
    float S=0.f;
    #pragma unroll
    for(int ck=0;ck<CK_;ck++){
        int idx=(pair*CK_+ck)*16+n;
        Sb[idx]=S;
        S=fmaf(Ap[idx],S,Ho[idx]);
    }
}

// pass 3: replay chunk from correct init; emit y = C.h + D*x
__global__ __launch_bounds__(256) void k_scan3(
    const float* __restrict__ dtT, const float* __restrict__ sxT,
    const float* __restrict__ BC, const float* __restrict__ A_log,
    const float* __restrict__ Dsk, const float* __restrict__ Sb,
    float* __restrict__ y)
{
    int wv=threadIdx.x>>6, lane=threadIdx.x&63;
    int grp=lane>>4, n=lane&15;
    int blk=blockIdx.x, pg=blk>>4, ck=(blk&15)*4+wv;
    int pair=pg*4+grp, b=pair>>8, c=pair&255;
    float An=-__expf(A_log[c*16+n]);
    float Dc=Dsk[c];
    int l0=ck*CL_;
    const float4* dp=(const float4*)(dtT+((size_t)(b*C_+c))*L_+l0);
    const float4* xp=(const float4*)(sxT+((size_t)(b*C_+c))*L_+l0);
    const float* bcp=BC+((size_t)b*L_+l0)*32;
    float* yp=y+((size_t)b*L_+l0)*C_+c;
    float carry=Sb[(pair*CK_+ck)*16+n];
    #pragma unroll
    for(int q=0;q<CL_/4;q++){
        float4 d4=dp[q], x4=xp[q];
        #pragma unroll
        for(int s2=0;s2<4;s2++){
            int st=4*q+s2;
            float dtv=(s2==0)?d4.x:(s2==1)?d4.y:(s2==2)?d4.z:d4.w;
            float xv =(s2==0)?x4.x:(s2==1)?x4.y:(s2==2)?x4.z:x4.w;
            float bv=bcp[st*32+n];
            float cv=bcp[st*32+16+n];
            float dA=__expf(dtv*An);
            carry=fmaf(dA,carry,dtv*bv*xv);
            float part=carry*cv;
            part+=__shfl_xor(part,1);
            part+=__shfl_xor(part,2);
            part+=__shfl_xor(part,4);
            part+=__shfl_xor(part,8);
            if(n==0) yp[(size_t)st*C_]=fmaf(Dc,xv,part);
        }
    }
}

// ---------------- unflip + out-LN + gate by SiLU(z) -> y2 ----------------
__global__ __launch_bounds__(256) void k_post(
    const float* __restrict__ y, const float* __restrict__ z,
    const float* __restrict__ og, const float* __restrict__ ob,
    float* __restrict__ y2, int ori)
{
    __shared__ float red[8];
    int c=threadIdx.x;
    int bl=blockIdx.x, b=bl>>12, l=bl&4095;
    int d=l&15, w=(l>>4)&15, h=l>>8;
    int hf=(ori&1)?15-h:h, wf=(ori&2)?15-w:w, df=(ori&4)?15-d:d;
    int lf=(hf*16+wf)*16+df;
    float v=y[((size_t)b*L_+lf)*C_+c];
    float s=v, ss=v*v;
    #pragma unroll
    for(int m=32;m>=1;m>>=1){ s+=__shfl_xor(s,m); ss+=__shfl_xor(ss,m); }
    if((c&63)==0){ red[(c>>6)*2]=s; red[(c>>6)*2+1]=ss; }
    __syncthreads();
    s=red[0]+red[2]+red[4]+red[6];
    ss=red[1]+red[3]+red[5]+red[7];
    float mn=s*(1.f/256.f);
    float rstd=rsqrtf(ss*(1.f/256.f)-mn*mn+1e-5f);
    float yn=(v-mn)*rstd*og[c]+ob[c];
    float zv=z[((size_t)b*L_+l)*C_+c];
    y2[((size_t)b*L_+l)*C_+c]=yn*silu_(zv);
}

// ---------------- out GEMM (256x256) + residual into t ----------------
__global__ __launch_bounds__(256) void k_out(
    const float* __restrict__ y2, const float* __restrict__ ow,
    float* __restrict__ t)
{
    __shared__ float hb[16*256];
    int tid=threadIdx.x;
    size_t row0=(size_t)blockIdx.x*16;
    const float* src=y2+row0*C_;
    for(int k=0;k<16;k++) hb[k*256+tid]=src[k*256+tid];
    __syncthreads();
    float acc[16];
    #pragma unroll
    for(int i=0;i<16;i++)acc[i]=0.f;
    const float4* wr=(const float4*)(ow+(size_t)tid*C_);
    for(int k4=0;k4<64;k4++){
        float4 a=wr[k4];
        #pragma unroll
        for(int i=0;i<16;i++){
            const float4 hv=*(const float4*)&hb[i*256+k4*4];
            acc[i]=fmaf(hv.x,a.x,fmaf(hv.y,a.y,fmaf(hv.z,a.z,fmaf(hv.w,a.w,acc[i]))));
        }
    }
    float* tp=t+row0*C_+tid;
    #pragma unroll
    for(int i=0;i<16;i++) tp[(size_t)i*C_]+=acc[i];
}

// ---------------- final LN + transpose out: t -> out (B,C,D,H,W) ----------------
__global__ __launch_bounds__(256) void k_final(
    const float* __restrict__ t, const float* __restrict__ pg,
    const float* __restrict__ pb, float* __restrict__ out)
{
    __shared__ float tile[16*257];
    __shared__ float mrs[16][2];
    int blk=blockIdx.x, b=blk>>8, d=(blk>>4)&15, h=blk&15;
    int tid=threadIdx.x;
    for(int w2=0;w2<16;w2++){
        tile[w2*257+tid]=t[((size_t)b*L_+(h*16+w2)*16+d)*C_+tid];
    }
    __syncthreads();
    int r=tid>>4, p=tid&15;
    float s=0.f, ss=0.f;
    #pragma unroll
    for(int k=0;k<16;k++){ float v=tile[r*257+k*16+p]; s+=v; ss+=v*v; }
    #pragma unroll
    for(int m=1;m<16;m<<=1){ s+=__shfl_xor(s,m); ss+=__shfl_xor(ss,m); }
    if(p==0){ float mn=s*(1.f/256.f); mrs[r][0]=mn; mrs[r][1]=rsqrtf(ss*(1.f/256.f)-mn*mn+1e-5f); }
    __syncthreads();
    int w2=tid&15;
    for(int p2=0;p2<16;p2++){
        int c=(tid>>4)+16*p2;
        float v=tile[w2*257+c];
        float vn=(v-mrs[w2][0])*mrs[w2][1]*pg[c]+pb[c];
        out[((size_t)(b*C_+c))*4096 + d*256 + h*16 + w2]=vn;
    }
}

extern "C" void kernel_launch(void* const* d_in, const int* in_sizes, int n_in,
                              void* d_out, int out_size, void* d_ws, size_t ws_size,
                              hipStream_t stream)
{
    (void)in_sizes; (void)n_in; (void)out_size; (void)ws_size;
    const float* x      =(const float*)d_in[0];
    const float* in_w   =(const float*)d_in[1];
    const float* conv_w =(const float*)d_in[2];
    const float* conv_b =(const float*)d_in[3];
    const float* xproj_w=(const float*)d_in[4];
    const float* dt_w   =(const float*)d_in[5];
    const float* dt_b   =(const float*)d_in[6];
    const float* A_log  =(const float*)d_in[7];
    const float* D_skip =(const float*)d_in[8];
    const float* on_g   =(const float*)d_in[9];
    const float* on_b   =(const float*)d_in[10];
    const float* out_w  =(const float*)d_in[11];
    const float* ln1_g  =(const float*)d_in[12];
    const float* ln1_b  =(const float*)d_in[13];
    const float* post_g =(const float*)d_in[14];
    const float* post_b =(const float*)d_in[15];
    float* out=(float*)d_out;
    float* ws=(float*)d_ws;

    const size_t NBL=(size_t)BL_*C_;     // 2,097,152 floats
    float* t   = ws;                      // residual stream [B][L][C]
    float* xs  = ws +   NBL;              // in-proj x-path; later y2
    float* z   = ws + 2*NBL;
    float* seq = ws + 3*NBL;              // conv output [l][c]; later y
    float* dtT = ws + 4*NBL;              // dt, scan-major [b][c][l]
    float* BC  = ws + 5*NBL;              // [B*L][32] (Bm | Cm)
    float* Ap  = BC + (size_t)BL_*32;     // 512*CK_*16 chunk summaries
    float* Ho  = Ap + 512*CK_*16;
    float* Sb  = Ho + 512*CK_*16;
    float* sxT = out;                     // seq, scan-major [b][c][l] — aliases d_out (dead until k_final)

    k_t_in<<<512,256,0,stream>>>(x,t);
    for(int i=0;i<DEPTH_;i++){
        int ori=i&7;
        k_ln_inproj<<<512,256,0,stream>>>(t, in_w+(size_t)i*512*256, ln1_g+i*256, ln1_b+i*256, xs, z);
        k_conv<<<8192,256,0,stream>>>(xs, conv_w+(size_t)i*6912, conv_b+i*256, seq, ori);
        k_xproj<<<512,256,0,stream>>>(seq, xproj_w+(size_t)i*12288, dt_w+(size_t)i*4096, dt_b+i*256, dtT, sxT, BC);
        k_scan1<<<2048,256,0,stream>>>(dtT, sxT, BC, A_log+(size_t)i*4096, Ap, Ho);
        k_scan2<<<32,256,0,stream>>>(Ap, Ho, Sb);
        k_scan3<<<2048,256,0,stream>>>(dtT, sxT, BC, A_log+(size_t)i*4096, D_skip+i*256, Sb, seq);
        k_post<<<8192,256,0,stream>>>(seq, z, on_g+i*256, on_b+i*256, xs, ori);
        k_out<<<512,256,0,stream>>>(xs, out_w+(size_t)i*65536, t);
    }
    k_final<<<512,256,0,stream>>>(t, post_g, post_b, out);
}

// Round 4
// 848.329 us; speedup vs baseline: 1.5237x; 1.2724x over previous
//
#include <hip/hip_runtime.h>
#include <math.h>

#define B_ 2
#define C_ 256
#define L_ 4096
#define BL_ 8192
#define DEPTH_ 4
#define CK_ 64   // chunks per sequence
#define CL_ 64   // chunk length

typedef __attribute__((ext_vector_type(8))) short bf16x8;
typedef __attribute__((ext_vector_type(4))) float f32x4;
#define MFMA16 __builtin_amdgcn_mfma_f32_16x16x32_bf16

__device__ __forceinline__ float silu_(float x){ return x/(1.f+__expf(-x)); }
__device__ __forceinline__ float softplus_(float x){ return fmaxf(x,0.f)+log1pf(__expf(-fabsf(x))); }
__device__ __forceinline__ unsigned short f2b_(float f){
    union{float f;unsigned u;}v; v.f=f;
    unsigned r=(v.u + 0x7fffu + ((v.u>>16)&1u))>>16;
    return (unsigned short)r;
}

// ---------------- fp32 -> bf16 weight conversion ----------------
__global__ __launch_bounds__(256) void k_w2b(const float* __restrict__ src, unsigned short* __restrict__ dst)
{
    int i=blockIdx.x*256+threadIdx.x;
    float4 v=((const float4*)src)[i];
    ushort4 o; o.x=f2b_(v.x); o.y=f2b_(v.y); o.z=f2b_(v.z); o.w=f2b_(v.w);
    ((ushort4*)dst)[i]=o;
}

// ---------------- transpose in: x (B,C,D,H,W) -> t [B][L][C], l=(h*16+w)*16+d ----------------
__global__ __launch_bounds__(256) void k_t_in(const float* __restrict__ x, float* __restrict__ t)
{
    __shared__ float tile[16*257];
    int blk=blockIdx.x, b=blk>>8, d=(blk>>4)&15, h=blk&15;
    int tid=threadIdx.x;
    int w2=tid&15;
    for(int p=0;p<16;p++){
        int c=(tid>>4)+16*p;
        tile[w2*257+c]=x[((size_t)(b*C_+c))*4096 + d*256 + h*16 + w2];
    }
    __syncthreads();
    for(int k=0;k<16;k++){
        t[((size_t)b*L_+(h*16+k)*16+d)*C_+tid]=tile[k*257+tid];
    }
}

// ---------------- LN1: t -> hb (bf16 [M][256]) ----------------
__global__ __launch_bounds__(256) void k_ln(
    const float* __restrict__ t, const float* __restrict__ g,
    const float* __restrict__ be, unsigned short* __restrict__ hb)
{
    int wv=threadIdx.x>>6, lane=threadIdx.x&63;
    int row=blockIdx.x*4+wv;
    float4 v=((const float4*)(t+(size_t)row*C_))[lane];
    float s=v.x+v.y+v.z+v.w;
    float ss=v.x*v.x+v.y*v.y+v.z*v.z+v.w*v.w;
    #pragma unroll
    for(int m=1;m<64;m<<=1){ s+=__shfl_xor(s,m); ss+=__shfl_xor(ss,m); }
    float mn=s*(1.f/256.f);
    float rs=rsqrtf(ss*(1.f/256.f)-mn*mn+1e-5f);
    float4 gg=((const float4*)g)[lane];
    float4 bb=((const float4*)be)[lane];
    ushort4 o;
    o.x=f2b_((v.x-mn)*rs*gg.x+bb.x);
    o.y=f2b_((v.y-mn)*rs*gg.y+bb.y);
    o.z=f2b_((v.z-mn)*rs*gg.z+bb.z);
    o.w=f2b_((v.w-mn)*rs*gg.w+bb.w);
    ((ushort4*)(hb+(size_t)row*C_))[lane]=o;
}

// ---------------- MFMA GEMM: xs|z[m][n] = hb[m][k] * Wt[n][k] ; N=512 split ----------------
__global__ __launch_bounds__(256) void k_gemm_in(
    const unsigned short* __restrict__ Ab, const unsigned short* __restrict__ Wb,
    float* __restrict__ xs, float* __restrict__ z)
{
    int wv=threadIdx.x>>6, lane=threadIdx.x&63;
    int m0=blockIdx.x*64+(wv>>1)*32;
    int n0=blockIdx.y*64+(wv&1)*32;
    int la=lane&15, kg=lane>>4;
    f32x4 acc[2][2];
    #pragma unroll
    for(int i=0;i<2;i++)
        #pragma unroll
        for(int j=0;j<2;j++) acc[i][j]=(f32x4){0.f,0.f,0.f,0.f};
    const unsigned short* a0p=Ab+(size_t)(m0+la)*C_+kg*8;
    const unsigned short* a1p=Ab+(size_t)(m0+16+la)*C_+kg*8;
    const unsigned short* b0p=Wb+(size_t)(n0+la)*C_+kg*8;
    const unsigned short* b1p=Wb+(size_t)(n0+16+la)*C_+kg*8;
    #pragma unroll
    for(int kk=0;kk<C_;kk+=32){
        bf16x8 a0=*(const bf16x8*)(a0p+kk);
        bf16x8 a1=*(const bf16x8*)(a1p+kk);
        bf16x8 b0=*(const bf16x8*)(b0p+kk);
        bf16x8 b1=*(const bf16x8*)(b1p+kk);
        acc[0][0]=MFMA16(a0,b0,acc[0][0],0,0,0);
        acc[0][1]=MFMA16(a0,b1,acc[0][1],0,0,0);
        acc[1][0]=MFMA16(a1,b0,acc[1][0],0,0,0);
        acc[1][1]=MFMA16(a1,b1,acc[1][1],0,0,0);
    }
    #pragma unroll
    for(int mi=0;mi<2;mi++)
        #pragma unroll
        for(int nj=0;nj<2;nj++)
            #pragma unroll
            for(int r=0;r<4;r++){
                int m=m0+mi*16+kg*4+r;
                int n=n0+nj*16+la;
                float val=acc[mi][nj][r];
                if(n<256) xs[(size_t)m*C_+n]=val;
                else      z [(size_t)m*C_+(n-256)]=val;
            }
}

// ---------------- MFMA GEMM + residual: t[m][n] += y2b[m][k] * Wt[n][k] ----------------
__global__ __launch_bounds__(256) void k_gemm_out(
    const unsigned short* __restrict__ Ab, const unsigned short* __restrict__ Wb,
    float* __restrict__ t)
{
    int wv=threadIdx.x>>6, lane=threadIdx.x&63;
    int m0=blockIdx.x*64+(wv>>1)*32;
    int n0=blockIdx.y*64+(wv&1)*32;
    int la=lane&15, kg=lane>>4;
    f32x4 acc[2][2];
    #pragma unroll
    for(int i=0;i<2;i++)
        #pragma unroll
        for(int j=0;j<2;j++) acc[i][j]=(f32x4){0.f,0.f,0.f,0.f};
    const unsigned short* a0p=Ab+(size_t)(m0+la)*C_+kg*8;
    const unsigned short* a1p=Ab+(size_t)(m0+16+la)*C_+kg*8;
    const unsigned short* b0p=Wb+(size_t)(n0+la)*C_+kg*8;
    const unsigned short* b1p=Wb+(size_t)(n0+16+la)*C_+kg*8;
    #pragma unroll
    for(int kk=0;kk<C_;kk+=32){
        bf16x8 a0=*(const bf16x8*)(a0p+kk);
        bf16x8 a1=*(const bf16x8*)(a1p+kk);
        bf16x8 b0=*(const bf16x8*)(b0p+kk);
        bf16x8 b1=*(const bf16x8*)(b1p+kk);
        acc[0][0]=MFMA16(a0,b0,acc[0][0],0,0,0);
        acc[0][1]=MFMA16(a0,b1,acc[0][1],0,0,0);
        acc[1][0]=MFMA16(a1,b0,acc[1][0],0,0,0);
        acc[1][1]=MFMA16(a1,b1,acc[1][1],0,0,0);
    }
    #pragma unroll
    for(int mi=0;mi<2;mi++)
        #pragma unroll
        for(int nj=0;nj<2;nj++)
            #pragma unroll
            for(int r=0;r<4;r++){
                int m=m0+mi*16+kg*4+r;
                int n=n0+nj*16+la;
                float* tp=t+(size_t)m*C_+n;
                *tp=*tp+acc[mi][nj][r];
            }
}

// ---------------- depthwise conv3x3x3 + bias + SiLU + flip-write -> seq ----------------
__global__ __launch_bounds__(256) void k_conv(
    const float* __restrict__ xs, const float* __restrict__ cw,
    const float* __restrict__ cb, float* __restrict__ seq, int ori)
{
    __shared__ float wl[256*27];
    int tid=threadIdx.x;
    for(int j=tid;j<256*27;j+=256) wl[j]=cw[j];
    int bl=blockIdx.x;
    int b=bl>>12, l=bl&4095;
    int d=l&15, w=(l>>4)&15, h=l>>8;
    __syncthreads();
    const float* base=xs+((size_t)b*L_)*C_+tid;
    const float* wp=wl+tid*27;
    float acc=cb[tid];
    #pragma unroll
    for(int kh=0;kh<3;kh++){
        int hh=h+kh-1; if((unsigned)hh>=16u) continue;
        #pragma unroll
        for(int kw=0;kw<3;kw++){
            int ww=w+kw-1; if((unsigned)ww>=16u) continue;
            #pragma unroll
            for(int kd=0;kd<3;kd++){
                int dd=d+kd-1; if((unsigned)dd>=16u) continue;
                acc=fmaf(wp[(kh*3+kw)*3+kd], base[(size_t)((hh*16+ww)*16+dd)*C_], acc);
            }
        }
    }
    acc=silu_(acc);
    int hf=(ori&1)?15-h:h;
    int wf=(ori&2)?15-w:w;
    int df=(ori&4)?15-d:d;
    seq[((size_t)b*L_+(hf*16+wf)*16+df)*C_+tid]=acc;
}

// ---------------- xproj (48 cols) + dt proj (softplus) + emit scan-major dtT/sxT ----------------
__global__ __launch_bounds__(256) void k_xproj(
    const float* __restrict__ seq, const float* __restrict__ xw,
    const float* __restrict__ dtw, const float* __restrict__ dtbias,
    float* __restrict__ dtT, float* __restrict__ sxT, float* __restrict__ BC)
{
    __shared__ float hb[16*256];
    __shared__ float dbl[16][48];
    int tid=threadIdx.x;
    size_t row0=(size_t)blockIdx.x*16;
    int b=(int)(row0>>12), lloc=(int)(row0&4095);
    const float* src=seq+row0*C_;
    for(int k=0;k<16;k++) hb[k*256+tid]=src[k*256+tid];
    __syncthreads();
    {
        int r=tid>>4, j=tid&15;
        const float4* wa=(const float4*)(xw+(size_t)j*C_);
        const float4* wb=(const float4*)(xw+(size_t)(j+16)*C_);
        const float4* wc=(const float4*)(xw+(size_t)(j+32)*C_);
        float a=0.f,b2=0.f,c=0.f;
        for(int k4=0;k4<64;k4++){
            const float4 hv=*(const float4*)&hb[r*256+k4*4];
            float4 xa=wa[k4],xb=wb[k4],xc=wc[k4];
            a =fmaf(hv.x,xa.x,fmaf(hv.y,xa.y,fmaf(hv.z,xa.z,fmaf(hv.w,xa.w,a ))));
            b2=fmaf(hv.x,xb.x,fmaf(hv.y,xb.y,fmaf(hv.z,xb.z,fmaf(hv.w,xb.w,b2))));
            c =fmaf(hv.x,xc.x,fmaf(hv.y,xc.y,fmaf(hv.z,xc.z,fmaf(hv.w,xc.w,c ))));
        }
        dbl[r][j]=a; dbl[r][j+16]=b2; dbl[r][j+32]=c;
    }
    __syncthreads();
    {
        int e=tid, r2=e>>5, j2=e&31;
        BC[(row0+r2)*32+j2]=dbl[r2][16+j2];
        e=tid+256; r2=e>>5; j2=e&31;
        BC[(row0+r2)*32+j2]=dbl[r2][16+j2];
    }
    {
        float* sp = sxT + ((size_t)(b*C_+tid))*L_ + lloc;
        #pragma unroll
        for(int q=0;q<4;q++){
            float4 v=make_float4(hb[(4*q+0)*256+tid],hb[(4*q+1)*256+tid],
                                 hb[(4*q+2)*256+tid],hb[(4*q+3)*256+tid]);
            ((float4*)sp)[q]=v;
        }
    }
    float wreg[16];
    #pragma unroll
    for(int j=0;j<16;j++) wreg[j]=dtw[tid*16+j];
    float bb=dtbias[tid];
    float dts[16];
    #pragma unroll
    for(int r2=0;r2<16;r2++){
        float acc=bb;
        #pragma unroll
        for(int j=0;j<16;j++) acc=fmaf(dbl[r2][j],wreg[j],acc);
        dts[r2]=softplus_(acc);
    }
    float* dp = dtT + ((size_t)(b*C_+tid))*L_ + lloc;
    #pragma unroll
    for(int q=0;q<4;q++){
        ((float4*)dp)[q]=make_float4(dts[4*q+0],dts[4*q+1],dts[4*q+2],dts[4*q+3]);
    }
}

// ---------------- chunked selective scan ----------------
__global__ __launch_bounds__(256) void k_scan1(
    const float* __restrict__ dtT, const float* __restrict__ sxT,
    const float* __restrict__ BC, const float* __restrict__ A_log,
    float* __restrict__ Ap, float* __restrict__ Ho)
{
    int wv=threadIdx.x>>6, lane=threadIdx.x&63;
    int grp=lane>>4, n=lane&15;
    int blk=blockIdx.x, pg=blk>>4, ck=(blk&15)*4+wv;
    int pair=pg*4+grp, b=pair>>8, c=pair&255;
    float An=-__expf(A_log[c*16+n]);
    int l0=ck*CL_;
    const float4* dp=(const float4*)(dtT+((size_t)(b*C_+c))*L_+l0);
    const float4* xp=(const float4*)(sxT+((size_t)(b*C_+c))*L_+l0);
    const float* bcp=BC+((size_t)b*L_+l0)*32+n;
    float carry=0.f, sdt=0.f;
    #pragma unroll
    for(int q=0;q<CL_/4;q++){
        float4 d4=dp[q], x4=xp[q];
        float bv;
        bv=bcp[(4*q+0)*32];{float dA=__expf(d4.x*An);carry=fmaf(dA,carry,d4.x*bv*x4.x);sdt+=d4.x;}
        bv=bcp[(4*q+1)*32];{float dA=__expf(d4.y*An);carry=fmaf(dA,carry,d4.y*bv*x4.y);sdt+=d4.y;}
        bv=bcp[(4*q+2)*32];{float dA=__expf(d4.z*An);carry=fmaf(dA,carry,d4.z*bv*x4.z);sdt+=d4.z;}
        bv=bcp[(4*q+3)*32];{float dA=__expf(d4.w*An);carry=fmaf(dA,carry,d4.w*bv*x4.w);sdt+=d4.w;}
    }
    int idx=(pair*CK_+ck)*16+n;
    Ap[idx]=__expf(An*sdt); Ho[idx]=carry;
}

__global__ __launch_bounds__(256) void k_scan2(
    const float* __restrict__ Ap, const float* __restrict__ Ho, float* __restrict__ Sb)
{
    int gid=blockIdx.x*256+threadIdx.x;
    int pair=gid>>4, n=gid&15;
    float S=0.f;
    #pragma unroll
    for(int ck=0;ck<CK_;ck++){
        int idx=(pair*CK_+ck)*16+n;
        Sb[idx]=S;
        S=fmaf(Ap[idx],S,Ho[idx]);
    }
}

__global__ __launch_bounds__(256) void k_scan3(
    const float* __restrict__ dtT, const float* __restrict__ sxT,
    const float* __restrict__ BC, const float* __restrict__ A_log,
    const float* __restrict__ Dsk, const float* __restrict__ Sb,
    float* __restrict__ y)
{
    int wv=threadIdx.x>>6, lane=threadIdx.x&63;
    int grp=lane>>4, n=lane&15;
    int blk=blockIdx.x, pg=blk>>4, ck=(blk&15)*4+wv;
    int pair=pg*4+grp, b=pair>>8, c=pair&255;
    float An=-__expf(A_log[c*16+n]);
    float Dc=Dsk[c];
    int l0=ck*CL_;
    const float4* dp=(const float4*)(dtT+((size_t)(b*C_+c))*L_+l0);
    const float4* xp=(const float4*)(sxT+((size_t)(b*C_+c))*L_+l0);
    const float* bcp=BC+((size_t)b*L_+l0)*32;
    float* yp=y+((size_t)b*L_+l0)*C_+c;
    float carry=Sb[(pair*CK_+ck)*16+n];
    #pragma unroll
    for(int q=0;q<CL_/4;q++){
        float4 d4=dp[q], x4=xp[q];
        #pragma unroll
        for(int s2=0;s2<4;s2++){
            int st=4*q+s2;
            float dtv=(s2==0)?d4.x:(s2==1)?d4.y:(s2==2)?d4.z:d4.w;
            float xv =(s2==0)?x4.x:(s2==1)?x4.y:(s2==2)?x4.z:x4.w;
            float bv=bcp[st*32+n];
            float cv=bcp[st*32+16+n];
            float dA=__expf(dtv*An);
            carry=fmaf(dA,carry,dtv*bv*xv);
            float part=carry*cv;
            part+=__shfl_xor(part,1);
            part+=__shfl_xor(part,2);
            part+=__shfl_xor(part,4);
            part+=__shfl_xor(part,8);
            if(n==0) yp[(size_t)st*C_]=fmaf(Dc,xv,part);
        }
    }
}

// ---------------- unflip + out-LN + gate by SiLU(z) -> y2b (bf16) ----------------
__global__ __launch_bounds__(256) void k_post(
    const float* __restrict__ y, const float* __restrict__ z,
    const float* __restrict__ og, const float* __restrict__ ob,
    unsigned short* __restrict__ y2b, int ori)
{
    __shared__ float red[8];
    int c=threadIdx.x;
    int bl=blockIdx.x, b=bl>>12, l=bl&4095;
    int d=l&15, w=(l>>4)&15, h=l>>8;
    int hf=(ori&1)?15-h:h, wf=(ori&2)?15-w:w, df=(ori&4)?15-d:d;
    int lf=(hf*16+wf)*16+df;
    float v=y[((size_t)b*L_+lf)*C_+c];
    float s=v, ss=v*v;
    #pragma unroll
    for(int m=32;m>=1;m>>=1){ s+=__shfl_xor(s,m); ss+=__shfl_xor(ss,m); }
    if((c&63)==0){ red[(c>>6)*2]=s; red[(c>>6)*2+1]=ss; }
    __syncthreads();
    s=red[0]+red[2]+red[4]+red[6];
    ss=red[1]+red[3]+red[5]+red[7];
    float mn=s*(1.f/256.f);
    float rstd=rsqrtf(ss*(1.f/256.f)-mn*mn+1e-5f);
    float yn=(v-mn)*rstd*og[c]+ob[c];
    float zv=z[((size_t)b*L_+l)*C_+c];
    y2b[((size_t)b*L_+l)*C_+c]=f2b_(yn*silu_(zv));
}

// ---------------- final LN + transpose out ----------------
__global__ __launch_bounds__(256) void k_final(
    const float* __restrict__ t, const float* __restrict__ pg,
    const float* __restrict__ pb, float* __restrict__ out)
{
    __shared__ float tile[16*257];
    __shared__ float mrs[16][2];
    int blk=blockIdx.x, b=blk>>8, d=(blk>>4)&15, h=blk&15;
    int tid=threadIdx.x;
    for(int w2=0;w2<16;w2++){
        tile[w2*257+tid]=t[((size_t)b*L_+(h*16+w2)*16+d)*C_+tid];
    }
    __syncthreads();
    int r=tid>>4, p=tid&15;
    float s=0.f, ss=0.f;
    #pragma unroll
    for(int k=0;k<16;k++){ float v=tile[r*257+k*16+p]; s+=v; ss+=v*v; }
    #pragma unroll
    for(int m=1;m<16;m<<=1){ s+=__shfl_xor(s,m); ss+=__shfl_xor(ss,m); }
    if(p==0){ float mn=s*(1.f/256.f); mrs[r][0]=mn; mrs[r][1]=rsqrtf(ss*(1.f/256.f)-mn*mn+1e-5f); }
    __syncthreads();
    int w2=tid&15;
    for(int p2=0;p2<16;p2++){
        int c=(tid>>4)+16*p2;
        float v=tile[w2*257+c];
        float vn=(v-mrs[w2][0])*mrs[w2][1]*pg[c]+pb[c];
        out[((size_t)(b*C_+c))*4096 + d*256 + h*16 + w2]=vn;
    }
}

extern "C" void kernel_launch(void* const* d_in, const int* in_sizes, int n_in,
                              void* d_out, int out_size, void* d_ws, size_t ws_size,
                              hipStream_t stream)
{
    (void)in_sizes; (void)n_in; (void)out_size; (void)ws_size;
    const float* x      =(const float*)d_in[0];
    const float* in_w   =(const float*)d_in[1];
    const float* conv_w =(const float*)d_in[2];
    const float* conv_b =(const float*)d_in[3];
    const float* xproj_w=(const float*)d_in[4];
    const float* dt_w   =(const float*)d_in[5];
    const float* dt_b   =(const float*)d_in[6];
    const float* A_log  =(const float*)d_in[7];
    const float* D_skip =(const float*)d_in[8];
    const float* on_g   =(const float*)d_in[9];
    const float* on_b   =(const float*)d_in[10];
    const float* out_w  =(const float*)d_in[11];
    const float* ln1_g  =(const float*)d_in[12];
    const float* ln1_b  =(const float*)d_in[13];
    const float* post_g =(const float*)d_in[14];
    const float* post_b =(const float*)d_in[15];
    float* out=(float*)d_out;
    float* ws=(float*)d_ws;

    const size_t NBL=(size_t)BL_*C_;     // 2,097,152 elems
    float* t   = ws;                      // residual stream [B][L][C]
    float* xs  = ws +   NBL;              // in-proj x-path
    float* z   = ws + 2*NBL;
    float* seq = ws + 3*NBL;              // conv output [l][c]; later y
    float* dtT = ws + 4*NBL;              // dt, scan-major [b][c][l]
    float* BC  = ws + 5*NBL;              // [B*L][32] (Bm | Cm)
    float* Ap  = BC + (size_t)BL_*32;
    float* Ho  = Ap + 512*CK_*16;
    float* Sb  = Ho + 512*CK_*16;
    unsigned short* hb  = (unsigned short*)(Sb + 512*CK_*16);  // bf16 LN'd activations [M][256]
    unsigned short* y2b = hb  + NBL;                           // bf16 gated output [M][256]
    unsigned short* wbI = y2b + NBL;                           // bf16 in_w  (4*512*256)
    unsigned short* wbO = wbI + (size_t)DEPTH_*512*C_;         // bf16 out_w (4*256*256)
    float* sxT = out;                     // seq, scan-major [b][c][l] — aliases d_out (dead until k_final)

    k_w2b<<<DEPTH_*512*C_/1024,256,0,stream>>>(in_w, wbI);
    k_w2b<<<DEPTH_*C_*C_/1024,256,0,stream>>>(out_w, wbO);
    k_t_in<<<512,256,0,stream>>>(x,t);
    for(int i=0;i<DEPTH_;i++){
        int ori=i&7;
        k_ln<<<2048,256,0,stream>>>(t, ln1_g+i*256, ln1_b+i*256, hb);
        k_gemm_in<<<dim3(128,8),256,0,stream>>>(hb, wbI+(size_t)i*512*C_, xs, z);
        k_conv<<<8192,256,0,stream>>>(xs, conv_w+(size_t)i*6912, conv_b+i*256, seq, ori);
        k_xproj<<<512,256,0,stream>>>(seq, xproj_w+(size_t)i*12288, dt_w+(size_t)i*4096, dt_b+i*256, dtT, sxT, BC);
        k_scan1<<<2048,256,0,stream>>>(dtT, sxT, BC, A_log+(size_t)i*4096, Ap, Ho);
        k_scan2<<<32,256,0,stream>>>(Ap, Ho, Sb);
        k_scan3<<<2048,256,0,stream>>>(dtT, sxT, BC, A_log+(size_t)i*4096, D_skip+i*256, Sb, seq);
        k_post<<<8192,256,0,stream>>>(seq, z, on_g+i*256, on_b+i*256, y2b, ori);
        k_gemm_out<<<dim3(128,4),256,0,stream>>>(y2b, wbO+(size_t)i*C_*C_, t);
    }
    k_final<<<512,256,0,stream>>>(t, post_g, post_b, out);
}